// Round 8
// baseline (17659.061 us; speedup 1.0000x reference)
//
#include <hip/hip_runtime.h>

#define B_ 512
#define T_ 256
#define D_ 128
#define H_ 512

typedef __bf16 bf16x8 __attribute__((ext_vector_type(8)));
typedef float f32x4 __attribute__((ext_vector_type(4)));
typedef unsigned long long u64;

__device__ __forceinline__ float sigm(float x) { return 1.f / (1.f + __expf(-x)); }
__device__ __forceinline__ float tanh_(float x) { return 2.f / (1.f + __expf(-2.f * x)) - 1.f; }

__device__ __forceinline__ void split2(float v, __bf16& hi, __bf16& lo) {
    hi = (__bf16)v;
    lo = (__bf16)(v - (float)hi);
}

// agent-scope (device-coherent) 8B load/store
__device__ __forceinline__ u64 cload(const __bf16* p) {
    return __hip_atomic_load((const u64*)p, __ATOMIC_RELAXED, __HIP_MEMORY_SCOPE_AGENT);
}
__device__ __forceinline__ void cstore(__bf16* p, u64 v) {
    __hip_atomic_store((u64*)p, v, __ATOMIC_RELAXED, __HIP_MEMORY_SCOPE_AGENT);
}

union UQ { uint4 q; bf16x8 v; u64 u[2]; };

// mirror 16B load: pure -> plain (L2-local), impure -> agent
template <bool PURE>
__device__ __forceinline__ uint4 mld16(const __bf16* p) {
    if constexpr (PURE) return *reinterpret_cast<const uint4*>(p);
    UQ r; r.u[0] = cload(p); r.u[1] = cload(p + 4); return r.q;
}
template <bool PURE>
__device__ __forceinline__ void mst8(__bf16* p, u64 v) {
    if constexpr (PURE) *reinterpret_cast<u64*>(p) = v;
    else cstore(p, v);
}

// ---------------- weight convert: fp32 -> split bf16 (hi+lo), transposed [N][K] ----------------
__global__ void k_convert(const float* __restrict__ k0, const float* __restrict__ r0,
                          const float* __restrict__ k1, const float* __restrict__ r1,
                          const float* __restrict__ W,
                          __bf16* __restrict__ wB0Th, __bf16* __restrict__ wB0Tl,
                          __bf16* __restrict__ wB1Th, __bf16* __restrict__ wB1Tl,
                          __bf16* __restrict__ wWTh,  __bf16* __restrict__ wWTl)
{
    int tid = blockIdx.x * blockDim.x + threadIdx.x;
    int nth = gridDim.x * blockDim.x;
    for (int idx = tid; idx < 640 * 2048; idx += nth) {
        int k = idx >> 11, n = idx & 2047;
        float v = (k < 128) ? k0[k * 2048 + n] : r0[(k - 128) * 2048 + n];
        split2(v, wB0Th[n * 640 + k], wB0Tl[n * 640 + k]);
    }
    for (int idx = tid; idx < 1024 * 2048; idx += nth) {
        int k = idx >> 11, n = idx & 2047;
        float v = (k < 512) ? k1[k * 2048 + n] : r1[(k - 512) * 2048 + n];
        split2(v, wB1Th[n * 1024 + k], wB1Tl[n * 1024 + k]);
    }
    for (int idx = tid; idx < 512 * 128; idx += nth) {
        int k = idx >> 7, n = idx & 127;
        split2(W[k * 128 + n], wWTh[n * 512 + k], wWTl[n * 512 + k]);
    }
}

// ---------------- init: zero mirrors, c-state, counters; census arrays ----------------
__global__ void k_init(unsigned int* __restrict__ mirz, int mirN,   // mirror block as u32
                       float* __restrict__ c0, float* __restrict__ c1,
                       int* __restrict__ cnt, int* __restrict__ grpcnt,
                       int* __restrict__ first, int* __restrict__ purity)
{
    int tid = blockIdx.x * blockDim.x + threadIdx.x;
    int nth = gridDim.x * blockDim.x;
    for (int i = tid; i < mirN; i += nth) mirz[i] = 0;
    for (int i = tid; i < B_ * H_; i += nth) { c0[i] = 0.f; c1[i] = 0.f; }
    for (int i = tid; i < 1024; i += nth) cnt[i] = 0;
    for (int i = tid; i < 8192; i += nth) grpcnt[i] = 0;
    if (tid < 8) { first[tid] = -1; purity[tid] = 1; }
}

// ---------------- barriers ----------------
__device__ __forceinline__ void gbar(int* cnt, int k) {
    asm volatile("s_waitcnt vmcnt(0)" ::: "memory");
    __syncthreads();
    if (threadIdx.x == 0) {
        __hip_atomic_fetch_add(&cnt[k], 1, __ATOMIC_RELAXED, __HIP_MEMORY_SCOPE_AGENT);
        while (__hip_atomic_load(&cnt[k], __ATOMIC_RELAXED, __HIP_MEMORY_SCOPE_AGENT) < 256)
            __builtin_amdgcn_s_sleep(1);
    }
    __syncthreads();
}
__device__ __forceinline__ void grpbar(int* cnt, int k) {
    asm volatile("s_waitcnt vmcnt(0)" ::: "memory");
    __syncthreads();
    if (threadIdx.x == 0) {
        __hip_atomic_fetch_add(&cnt[k], 1, __ATOMIC_RELAXED, __HIP_MEMORY_SCOPE_AGENT);
        while (__hip_atomic_load(&cnt[k], __ATOMIC_RELAXED, __HIP_MEMORY_SCOPE_AGENT) < 32)
            __builtin_amdgcn_s_sleep(1);
    }
    __syncthreads();
}

// ---------------- group mirror fill: h-global (agent) -> group mirror ----------------
template <bool PURE>
__device__ __forceinline__ void fillmir(__bf16* dh, __bf16* dl,
                                        const __bf16* sh, const __bf16* sl,
                                        int mg, int sub, int tid)
{
#pragma unroll
    for (int i = 0; i < 2; ++i) {
        int e = tid * 2 + i;                 // 0..1023 u64 chunks per buffer
        int lrow = sub * 8 + (e >> 7);       // 8 rows per WG
        int c4 = (e & 127) * 4;
        size_t soff = (size_t)(mg * 256 + lrow) * 512 + c4;
        size_t doff = (size_t)lrow * 512 + c4;
        u64 vh = cload(sh + soff);
        u64 vl = cload(sl + soff);
        mst8<PURE>(dh + doff, vh);
        mst8<PURE>(dl + doff, vl);
    }
}

// ---------------- pred fused: h1m @ W^T + bo -> impute -> cur-in-LDS (swizzled) ----------------
template <bool PURE>
__device__ __forceinline__ void predphase(
    const __bf16* h1mh, const __bf16* h1ml,
    const __bf16* WTh, const __bf16* WTl,
    const float* bo, const float* x, int t,
    float* outPred, int m0, int lr0, int g, int tid,
    __bf16* cuH, __bf16* cuL)
{
    const int lane = tid & 63, wave = tid >> 6;
    const int rowsub = wave >> 1;          // 0..3
    const int cbase = (wave & 1) * 4;      // 4 col-tiles per wave
    const int rW = rowsub * 16 + (lane & 15);   // row within WG 64-tile
    const int lrow = lr0 + rW;
    const int kof = (lane >> 4) << 3;

    f32x4 acc[4] = {};
#pragma unroll 2
    for (int kb = 0; kb < 512; kb += 32) {
        int k = kb + kof;
        UQ ah, al;
        ah.q = mld16<PURE>(h1mh + (size_t)lrow * 512 + k);
        al.q = mld16<PURE>(h1ml + (size_t)lrow * 512 + k);
#pragma unroll
        for (int i = 0; i < 4; ++i) {
            const __bf16* wb = WTh + (size_t)((cbase + i) * 16 + (lane & 15)) * 512 + k;
            const __bf16* wl = WTl + (size_t)((cbase + i) * 16 + (lane & 15)) * 512 + k;
            UQ bh, bl; bh.q = *reinterpret_cast<const uint4*>(wb);
            bl.q = *reinterpret_cast<const uint4*>(wl);
            acc[i] = __builtin_amdgcn_mfma_f32_16x16x32_bf16(bh.v, ah.v, acc[i], 0, 0, 0);
            acc[i] = __builtin_amdgcn_mfma_f32_16x16x32_bf16(bl.v, ah.v, acc[i], 0, 0, 0);
            acc[i] = __builtin_amdgcn_mfma_f32_16x16x32_bf16(bh.v, al.v, acc[i], 0, 0, 0);
        }
    }
    const int swz = (rW & 7) << 3;
#pragma unroll
    for (int i = 0; i < 4; ++i) {
        int colb = (cbase + i) * 16 + ((lane >> 4) << 2);
        f32x4 bo4 = *reinterpret_cast<const f32x4*>(&bo[colb]);
        int gr = m0 + rW;
        f32x4 xv4 = *reinterpret_cast<const f32x4*>(&x[((size_t)gr * T_ + t) * D_ + colb]);
        f32x4 p4;
        union { __bf16 b[4]; u64 u; } ch, cl;
#pragma unroll
        for (int r = 0; r < 4; ++r) {
            float pred = acc[i][r] + bo4[r];
            p4[r] = pred;
            float cv = (xv4[r] == 128.0f) ? pred : xv4[r];
            split2(cv, ch.b[r], cl.b[r]);
        }
        if (g < 2)
            *reinterpret_cast<f32x4*>(&outPred[((size_t)gr * (T_ - 1) + (t - 1)) * D_ + colb]) = p4;
        int addr = rW * 144 + (((colb & ~7) ^ swz) | (colb & 7));
        *reinterpret_cast<u64*>(&cuH[addr]) = ch.u;
        *reinterpret_cast<u64*>(&cuL[addr]) = cl.u;
    }
}

// t==0: cur = x[:,0,:]
__device__ __forceinline__ void curfill_x(const float* x, int m0, int tid,
                                          __bf16* cuH, __bf16* cuL)
{
    const int rW = tid >> 3;
    const int kc0 = (tid & 7) * 16;
    const int swz = (rW & 7) << 3;
#pragma unroll
    for (int h = 0; h < 2; ++h) {
        int kc = kc0 + h * 8;
        union { __bf16 b[8]; uint4 q; } vh, vl;
#pragma unroll
        for (int e = 0; e < 8; ++e) {
            float xv = x[((size_t)(m0 + rW) * T_ + 0) * D_ + kc + e];
            split2(xv, vh.b[e], vl.b[e]);
        }
        int addr = rW * 144 + (kc ^ swz);
        *reinterpret_cast<uint4*>(&cuH[addr]) = vh.q;
        *reinterpret_cast<uint4*>(&cuL[addr]) = vl.q;
    }
}

// ---------------- layer GEMM phase (r6 k_layer adapted to mirror A) ----------------
// CURLDS: first BK=128 tile of A comes from cur-LDS (layer0 only).
template <int KTOT, int K1, bool CURLDS, bool PURE>
__device__ __forceinline__ void layerK(
    const __bf16* A1h, const __bf16* A1l,      // mirror, row stride 512, local rows
    const __bf16* A2h, const __bf16* A2l,
    const __bf16* BTh, const __bf16* BTl,
    const float* bias, float* cst,
    __bf16* hgh, __bf16* hgl, float* hf32,
    int j0, int m0, int lr0, int tid,
    __bf16* sAh, __bf16* sAl, __bf16* sBh, __bf16* sBl, float* szred,
    const __bf16* cuH, const __bf16* cuL)
{
    constexpr int LSTR = 144;
    const int lane = tid & 63;
    const int wave = tid >> 6;
    const int wpair = wave >> 1;
    const int ksub = wave & 1;

    const int srow = tid >> 3;
    const int skc = (tid & 7) << 4;
    const int swz = (srow & 7) << 3;
    const int sw1 = srow * LSTR + (skc ^ swz);
    const int sw2 = srow * LSTR + ((skc + 8) ^ swz);
    const int bgrow = (srow >> 4) * 512 + j0 + (srow & 15);

    uint4 rA0 = {}, rA1 = {}, rAl0 = {}, rAl1 = {}, rB0, rB1, rBl0, rBl1;
    auto loadA = [&](int kb) {
        int k = kb + skc;
        const __bf16 *ah, *al; size_t off;
        if (!CURLDS && k < K1) { ah = A1h; al = A1l; off = (size_t)(lr0 + srow) * 512 + k; }
        else                   { ah = A2h; al = A2l; off = (size_t)(lr0 + srow) * 512 + (k - K1); }
        rA0 = mld16<PURE>(ah + off);
        rA1 = mld16<PURE>(ah + off + 8);
        rAl0 = mld16<PURE>(al + off);
        rAl1 = mld16<PURE>(al + off + 8);
    };
    auto loadB = [&](int kb) {
        size_t off = (size_t)bgrow * KTOT + kb + skc;
        rB0 = *reinterpret_cast<const uint4*>(BTh + off);
        rB1 = *reinterpret_cast<const uint4*>(BTh + off + 8);
        rBl0 = *reinterpret_cast<const uint4*>(BTl + off);
        rBl1 = *reinterpret_cast<const uint4*>(BTl + off + 8);
    };

    loadB(0);
    if (!CURLDS) loadA(0);

    f32x4 acc[4] = {};
    const int arow = wpair * 16 + (lane & 15);
    const int abase = arow * LSTR;
    const int aswz = (arow & 7) << 3;
    const int kfrag = ksub * 64 + ((lane >> 4) << 3);

    for (int kb = 0; kb < KTOT; kb += 128) {
        const bool curtile = CURLDS && kb == 0;
        __syncthreads();
        if (!curtile) {
            *reinterpret_cast<uint4*>(&sAh[sw1]) = rA0;
            *reinterpret_cast<uint4*>(&sAh[sw2]) = rA1;
            *reinterpret_cast<uint4*>(&sAl[sw1]) = rAl0;
            *reinterpret_cast<uint4*>(&sAl[sw2]) = rAl1;
        }
        *reinterpret_cast<uint4*>(&sBh[sw1]) = rB0;
        *reinterpret_cast<uint4*>(&sBh[sw2]) = rB1;
        *reinterpret_cast<uint4*>(&sBl[sw1]) = rBl0;
        *reinterpret_cast<uint4*>(&sBl[sw2]) = rBl1;
        if (kb + 128 < KTOT) { loadA(kb + 128); loadB(kb + 128); }
        __syncthreads();
        const __bf16* aH = curtile ? cuH : sAh;
        const __bf16* aL = curtile ? cuL : sAl;
#pragma unroll
        for (int kk = 0; kk < 2; ++kk) {
            int ko = kfrag + kk * 32;
            int ai = abase + (ko ^ aswz);
            bf16x8 a_h = *reinterpret_cast<const bf16x8*>(&aH[ai]);
            bf16x8 a_l = *reinterpret_cast<const bf16x8*>(&aL[ai]);
#pragma unroll
            for (int g = 0; g < 4; ++g) {
                int br = g * 16 + (lane & 15);
                int bi = br * LSTR + (ko ^ ((br & 7) << 3));
                bf16x8 b_h = *reinterpret_cast<const bf16x8*>(&sBh[bi]);
                bf16x8 b_l = *reinterpret_cast<const bf16x8*>(&sBl[bi]);
                acc[g] = __builtin_amdgcn_mfma_f32_16x16x32_bf16(b_h, a_h, acc[g], 0, 0, 0);
                acc[g] = __builtin_amdgcn_mfma_f32_16x16x32_bf16(b_l, a_h, acc[g], 0, 0, 0);
                acc[g] = __builtin_amdgcn_mfma_f32_16x16x32_bf16(b_h, a_l, acc[g], 0, 0, 0);
            }
        }
    }

    __syncthreads();
    if (ksub == 1) {
        float* zr = &szred[(wpair * 64 + lane) * 21];
#pragma unroll
        for (int g = 0; g < 4; ++g)
#pragma unroll
            for (int r = 0; r < 4; ++r)
                zr[g * 4 + r] = acc[g][r];
    }
    __syncthreads();
    if (ksub == 0) {
        const int grow = m0 + wpair * 16 + (lane & 15);
        const int colb = j0 + ((lane >> 4) << 2);
        const float* zr = &szred[(wpair * 64 + lane) * 21];
        f32x4 bi4 = *reinterpret_cast<const f32x4*>(&bias[colb]);
        f32x4 bf4 = *reinterpret_cast<const f32x4*>(&bias[512 + colb]);
        f32x4 bg4 = *reinterpret_cast<const f32x4*>(&bias[1024 + colb]);
        f32x4 bo4 = *reinterpret_cast<const f32x4*>(&bias[1536 + colb]);
        f32x4 c4 = *reinterpret_cast<f32x4*>(&cst[(size_t)grow * H_ + colb]);
        union { __bf16 b[4]; u64 u; } hh, hl;
        f32x4 h4;
#pragma unroll
        for (int r = 0; r < 4; ++r) {
            float zi = acc[0][r] + zr[0 + r] + bi4[r];
            float zf = acc[1][r] + zr[4 + r] + bf4[r];
            float zg = acc[2][r] + zr[8 + r] + bg4[r];
            float zo = acc[3][r] + zr[12 + r] + bo4[r];
            float gi = sigm(zi), gf = sigm(zf), gg = tanh_(zg), go = sigm(zo);
            float c = gf * c4[r] + gi * gg;
            c4[r] = c;
            float h = go * tanh_(c);
            h4[r] = h;
            split2(h, hh.b[r], hl.b[r]);
        }
        *reinterpret_cast<f32x4*>(&cst[(size_t)grow * H_ + colb]) = c4;
        cstore(&hgh[(size_t)grow * H_ + colb], hh.u);
        cstore(&hgl[(size_t)grow * H_ + colb], hl.u);
        if (hf32) *reinterpret_cast<f32x4*>(&hf32[(size_t)grow * H_ + colb]) = h4;
    }
}

// ---------------- persistent kernel ----------------
struct KA {
    const float* x;
    const __bf16 *wB0Th, *wB0Tl, *wB1Th, *wB1Tl, *wWTh, *wWTl;
    const float *b0, *b1, *bo;
    __bf16 *h0gh, *h0gl, *h1gh, *h1gl;   // global h exchange
    __bf16 *mir;                          // 8 groups x 4 bufs x [256][512]
    float *c0, *c1;
    float *outPred, *lastcell;
    int *cnt, *grpcnt, *first, *purity;
};

template <bool PURE>
__device__ void run_T(const KA& a, char* smem, int wg)
{
    const int g = wg & 7, sub = wg >> 3;
    const int jg = g >> 1, mg = g & 1;
    const int jsub = sub >> 2, msub = sub & 3;
    const int j0 = (jg * 8 + jsub) * 16;
    const int m0 = (mg * 4 + msub) * 64;
    const int lr0 = msub * 64;
    const int tid = threadIdx.x;

    __bf16* sAh = (__bf16*)smem;
    __bf16* sAl = sAh + 64 * 144;
    __bf16* sBh = sAl + 64 * 144;
    __bf16* sBl = sBh + 64 * 144;
    float* szred = (float*)smem;
    __bf16* cuH = (__bf16*)(smem + 73728);
    __bf16* cuL = cuH + 64 * 144;

    __bf16* h0mh = a.mir + (size_t)(g * 4 + 0) * 131072;
    __bf16* h0ml = a.mir + (size_t)(g * 4 + 1) * 131072;
    __bf16* h1mh = a.mir + (size_t)(g * 4 + 2) * 131072;
    __bf16* h1ml = a.mir + (size_t)(g * 4 + 3) * 131072;
    int* gcnt = a.grpcnt + g * 1024;

    int ep = 1, gep = 0;
    for (int t = 0; t < T_; ++t) {
        // ---- P1': pred->cur (LDS), then layer0 ----
        if (t == 0) curfill_x(a.x, m0, tid, cuH, cuL);
        else predphase<PURE>(h1mh, h1ml, a.wWTh, a.wWTl, a.bo, a.x, t,
                             a.outPred, m0, lr0, g, tid, cuH, cuL);
        __syncthreads();
        layerK<640, 128, true, PURE>(h0mh, h0ml, h0mh, h0ml,
                                     a.wB0Th, a.wB0Tl, a.b0, a.c0,
                                     a.h0gh, a.h0gl, nullptr,
                                     j0, m0, lr0, tid, sAh, sAl, sBh, sBl, szred, cuH, cuL);
        gbar(a.cnt, ++ep);
        fillmir<PURE>(h0mh, h0ml, a.h0gh, a.h0gl, mg, sub, tid);
        grpbar(gcnt, ++gep);
        // ---- P2: layer1 ----
        layerK<1024, 512, false, PURE>(h0mh, h0ml, h1mh, h1ml,
                                       a.wB1Th, a.wB1Tl, a.b1, a.c1,
                                       a.h1gh, a.h1gl, (t == T_ - 1) ? a.lastcell : nullptr,
                                       j0, m0, lr0, tid, sAh, sAl, sBh, sBl, szred, cuH, cuL);
        gbar(a.cnt, ++ep);
        fillmir<PURE>(h1mh, h1ml, a.h1gh, a.h1gl, mg, sub, tid);
        grpbar(gcnt, ++gep);
    }
}

__global__ __launch_bounds__(512) void k_persistent(KA a)
{
    __shared__ __align__(16) char smem[110592];
    const int wg = blockIdx.x;
    const int g = wg & 7;

    if (threadIdx.x == 0) {
        int xcc;
        asm volatile("s_getreg_b32 %0, hwreg(20, 0, 32)" : "=s"(xcc));
        int old = atomicCAS(&a.first[g], -1, xcc);
        if (old != -1 && old != xcc) atomicExch(&a.purity[g], 0);
    }
    gbar(a.cnt, 1);
    int pure = __hip_atomic_load(&a.purity[g], __ATOMIC_RELAXED, __HIP_MEMORY_SCOPE_AGENT);
    if (pure) run_T<true>(a, smem, wg);
    else      run_T<false>(a, smem, wg);
}

extern "C" void kernel_launch(void* const* d_in, const int* in_sizes, int n_in,
                              void* d_out, int out_size, void* d_ws, size_t ws_size,
                              hipStream_t stream)
{
    const float* x  = (const float*)d_in[0];
    const float* k0 = (const float*)d_in[1];
    const float* r0 = (const float*)d_in[2];
    const float* b0 = (const float*)d_in[3];
    const float* k1 = (const float*)d_in[4];
    const float* r1 = (const float*)d_in[5];
    const float* b1 = (const float*)d_in[6];
    const float* W  = (const float*)d_in[7];
    const float* bo = (const float*)d_in[8];
    float* out = (float*)d_out;

    char* ws = (char*)d_ws;
    size_t off = 0;
    auto alloc = [&](size_t bytes) { void* p = ws + off; off += (bytes + 255) & ~255ull; return p; };
    __bf16* wB0Th = (__bf16*)alloc((size_t)2048 * 640 * 2);
    __bf16* wB0Tl = (__bf16*)alloc((size_t)2048 * 640 * 2);
    __bf16* wB1Th = (__bf16*)alloc((size_t)2048 * 1024 * 2);
    __bf16* wB1Tl = (__bf16*)alloc((size_t)2048 * 1024 * 2);
    __bf16* wWTh  = (__bf16*)alloc((size_t)128 * 512 * 2);
    __bf16* wWTl  = (__bf16*)alloc((size_t)128 * 512 * 2);
    __bf16* h0gh  = (__bf16*)alloc((size_t)B_ * H_ * 2);
    __bf16* h0gl  = (__bf16*)alloc((size_t)B_ * H_ * 2);
    __bf16* h1gh  = (__bf16*)alloc((size_t)B_ * H_ * 2);
    __bf16* h1gl  = (__bf16*)alloc((size_t)B_ * H_ * 2);
    __bf16* mir   = (__bf16*)alloc((size_t)8 * 4 * 256 * 512 * 2);   // 8.39 MB
    float* c0 = (float*)alloc((size_t)B_ * H_ * 4);
    float* c1 = (float*)alloc((size_t)B_ * H_ * 4);
    int* cnt    = (int*)alloc(1024 * sizeof(int));
    int* grpcnt = (int*)alloc(8192 * sizeof(int));
    int* first  = (int*)alloc(8 * sizeof(int));
    int* purity = (int*)alloc(8 * sizeof(int));

    k_convert<<<2048, 256, 0, stream>>>(k0, r0, k1, r1, W, wB0Th, wB0Tl, wB1Th, wB1Tl, wWTh, wWTl);
    k_init<<<1024, 256, 0, stream>>>((unsigned int*)mir, (int)((size_t)8 * 4 * 256 * 512 / 2),
                                     c0, c1, cnt, grpcnt, first, purity);

    float* lastcell = out + (size_t)B_ * (T_ - 1) * D_;

    KA a;
    a.x = x;
    a.wB0Th = wB0Th; a.wB0Tl = wB0Tl; a.wB1Th = wB1Th; a.wB1Tl = wB1Tl;
    a.wWTh = wWTh; a.wWTl = wWTl;
    a.b0 = b0; a.b1 = b1; a.bo = bo;
    a.h0gh = h0gh; a.h0gl = h0gl; a.h1gh = h1gh; a.h1gl = h1gl;
    a.mir = mir;
    a.c0 = c0; a.c1 = c1;
    a.outPred = out; a.lastcell = lastcell;
    a.cnt = cnt; a.grpcnt = grpcnt; a.first = first; a.purity = purity;

    void* kargs[] = { &a };
    hipLaunchCooperativeKernel((const void*)k_persistent, dim3(256), dim3(512),
                               kargs, 0, stream);
}

// Round 9
// 5142.421 us; speedup vs baseline: 3.4340x; 3.4340x over previous
//
#include <hip/hip_runtime.h>

#define B_ 512
#define T_ 256
#define D_ 128
#define H_ 512

typedef _Float16 f16x8 __attribute__((ext_vector_type(8)));
typedef float f32x4 __attribute__((ext_vector_type(4)));
typedef unsigned long long u64;

__device__ __forceinline__ float sigm(float x) { return 1.f / (1.f + __expf(-x)); }
__device__ __forceinline__ float tanh_(float x) { return 2.f / (1.f + __expf(-2.f * x)) - 1.f; }

// ---------------- weight convert: fp32 -> fp16, transposed to [N][K] ----------------
__global__ void k_convert(const float* __restrict__ k0, const float* __restrict__ r0,
                          const float* __restrict__ k1, const float* __restrict__ r1,
                          const float* __restrict__ W,
                          _Float16* __restrict__ wB0T,  // [2048][640]
                          _Float16* __restrict__ wB1T,  // [2048][1024]
                          _Float16* __restrict__ wWT)   // [128][512]
{
    int tid = blockIdx.x * blockDim.x + threadIdx.x;
    int nth = gridDim.x * blockDim.x;
    for (int idx = tid; idx < 640 * 2048; idx += nth) {
        int k = idx >> 11, n = idx & 2047;
        float v = (k < 128) ? k0[k * 2048 + n] : r0[(k - 128) * 2048 + n];
        wB0T[n * 640 + k] = (_Float16)v;
    }
    for (int idx = tid; idx < 1024 * 2048; idx += nth) {
        int k = idx >> 11, n = idx & 2047;
        float v = (k < 512) ? k1[k * 2048 + n] : r1[(k - 512) * 2048 + n];
        wB1T[n * 1024 + k] = (_Float16)v;
    }
    for (int idx = tid; idx < 512 * 128; idx += nth) {
        int k = idx >> 7, n = idx & 127;
        wWT[n * 512 + k] = (_Float16)W[k * 128 + n];
    }
}

// ---------------- init: cur = x[:,0,:] fp16, zero h/c state ----------------
__global__ void k_init(const float* __restrict__ x, _Float16* __restrict__ cur,
                       _Float16* __restrict__ h0a, _Float16* __restrict__ h0b,
                       _Float16* __restrict__ h1a, _Float16* __restrict__ h1b,
                       float* __restrict__ c0, float* __restrict__ c1)
{
    int tid = blockIdx.x * blockDim.x + threadIdx.x;
    int nth = gridDim.x * blockDim.x;
    for (int idx = tid; idx < B_ * D_; idx += nth) {
        int b = idx >> 7, d = idx & 127;
        cur[idx] = (_Float16)x[b * (T_ * D_) + d];   // t=0: 128.0 exact in fp16
    }
    for (int idx = tid; idx < B_ * H_; idx += nth) {
        h0a[idx] = (_Float16)0.f; h0b[idx] = (_Float16)0.f;
        h1a[idx] = (_Float16)0.f; h1b[idx] = (_Float16)0.f;
        c0[idx] = 0.f; c1[idx] = 0.f;
    }
}

// ---------------- one LSTM layer step, fp16 GEMM, BK=128, swizzled LDS ----------------
// z^T fragments via swapped-operand MFMA: lane owns row m0+wpair*16+(lane&15),
// 4 consecutive cols j0+(lane>>4)*4..+3. A=[A1|A2] K-segments; BT [2048][KTOT].
// 8 waves: wpair=wave>>1 (16-row group), ksub=wave&1 (K-half of the 128 tile).
template <int KTOT, int K1>
__global__ __launch_bounds__(512) void k_layer(
    const _Float16* __restrict__ A1, int lda1,
    const _Float16* __restrict__ A2, int lda2,
    const _Float16* __restrict__ BT,
    const float* __restrict__ bias,       // [2048] gate order i,f,g,o
    float* __restrict__ cst,              // [512][512] fp32 rmw
    _Float16* __restrict__ hout,
    float* __restrict__ hout_f32)         // optional fp32 copy (last_cell)
{
    constexpr int LSTR = 144;
    __shared__ __align__(16) char smem[2 * 64 * LSTR * 2];   // 36864 B
    _Float16* sA = (_Float16*)smem;
    _Float16* sB = sA + 64 * LSTR;
    float* szred = (float*)smem;          // aliased after main loop (barrier-separated)

    const int j0 = blockIdx.x * 16;
    const int m0 = blockIdx.y * 64;
    const int tid = threadIdx.x;
    const int lane = tid & 63;
    const int wave = tid >> 6;
    const int wpair = wave >> 1;
    const int ksub = wave & 1;

    // staging: thread -> (row, 16-elem k chunk)
    const int srow = tid >> 3;
    const int skc = (tid & 7) << 4;       // 0,16,...,112
    const int swz = (srow & 7) << 3;
    const int sw1 = srow * LSTR + (skc ^ swz);
    const int sw2 = srow * LSTR + ((skc + 8) ^ swz);
    const int bgrow = (srow >> 4) * 512 + j0 + (srow & 15);

    uint4 rA0, rA1, rB0, rB1;
    auto loadA = [&](int kb) {
        int k = kb + skc;
        const _Float16* a; size_t off;
        if (k < K1) { a = A1; off = (size_t)(m0 + srow) * lda1 + k; }
        else        { a = A2; off = (size_t)(m0 + srow) * lda2 + (k - K1); }
        rA0 = *reinterpret_cast<const uint4*>(a + off);
        rA1 = *reinterpret_cast<const uint4*>(a + off + 8);
    };
    auto loadB = [&](int kb) {
        size_t off = (size_t)bgrow * KTOT + kb + skc;
        rB0 = *reinterpret_cast<const uint4*>(BT + off);
        rB1 = *reinterpret_cast<const uint4*>(BT + off + 8);
    };

    loadA(0); loadB(0);

    f32x4 acc[4] = {};
    const int arow = wpair * 16 + (lane & 15);
    const int abase = arow * LSTR;
    const int aswz = (arow & 7) << 3;
    const int kfrag = ksub * 64 + ((lane >> 4) << 3);

    for (int kb = 0; kb < KTOT; kb += 128) {
        __syncthreads();
        *reinterpret_cast<uint4*>(&sA[sw1]) = rA0;
        *reinterpret_cast<uint4*>(&sA[sw2]) = rA1;
        *reinterpret_cast<uint4*>(&sB[sw1]) = rB0;
        *reinterpret_cast<uint4*>(&sB[sw2]) = rB1;
        if (kb + 128 < KTOT) { loadA(kb + 128); loadB(kb + 128); }
        __syncthreads();
#pragma unroll
        for (int kk = 0; kk < 2; ++kk) {
            int ko = kfrag + kk * 32;
            f16x8 a = *reinterpret_cast<const f16x8*>(&sA[abase + (ko ^ aswz)]);
#pragma unroll
            for (int g = 0; g < 4; ++g) {
                int br = g * 16 + (lane & 15);
                f16x8 b = *reinterpret_cast<const f16x8*>(&sB[br * LSTR + (ko ^ ((br & 7) << 3))]);
                acc[g] = __builtin_amdgcn_mfma_f32_16x16x32_f16(b, a, acc[g], 0, 0, 0);
            }
        }
    }

    __syncthreads();                      // staging reads done; szred may alias
    if (ksub == 1) {
        float* zr = &szred[(wpair * 64 + lane) * 21];
#pragma unroll
        for (int g = 0; g < 4; ++g)
#pragma unroll
            for (int r = 0; r < 4; ++r)
                zr[g * 4 + r] = acc[g][r];
    }
    __syncthreads();
    if (ksub == 0) {
        const int row  = m0 + wpair * 16 + (lane & 15);
        const int colb = j0 + ((lane >> 4) << 2);
        const float* zr = &szred[(wpair * 64 + lane) * 21];
        f32x4 bi4 = *reinterpret_cast<const f32x4*>(&bias[colb]);
        f32x4 bf4 = *reinterpret_cast<const f32x4*>(&bias[512 + colb]);
        f32x4 bg4 = *reinterpret_cast<const f32x4*>(&bias[1024 + colb]);
        f32x4 bo4 = *reinterpret_cast<const f32x4*>(&bias[1536 + colb]);
        f32x4 c4 = *reinterpret_cast<f32x4*>(&cst[row * H_ + colb]);
        union { _Float16 h[4]; u64 u; } hh;
        f32x4 h4;
#pragma unroll
        for (int r = 0; r < 4; ++r) {
            float zi = acc[0][r] + zr[0 + r] + bi4[r];
            float zf = acc[1][r] + zr[4 + r] + bf4[r];
            float zg = acc[2][r] + zr[8 + r] + bg4[r];
            float zo = acc[3][r] + zr[12 + r] + bo4[r];
            float gi = sigm(zi), gf = sigm(zf), gg = tanh_(zg), go = sigm(zo);
            float c = gf * c4[r] + gi * gg;
            c4[r] = c;
            float h = go * tanh_(c);
            h4[r] = h;
            hh.h[r] = (_Float16)h;
        }
        *reinterpret_cast<f32x4*>(&cst[row * H_ + colb]) = c4;
        *reinterpret_cast<u64*>(&hout[row * H_ + colb]) = hh.u;
        if (hout_f32) *reinterpret_cast<f32x4*>(&hout_f32[row * H_ + colb]) = h4;
    }
}

// ---------------- pred: one 16x16 tile/WG, 8-wave K-split, direct frag loads ----------------
// Grid 256 WGs (32 b-row tiles x 8 d-col tiles), 512 threads.
__global__ __launch_bounds__(512) void k_pred(
    const _Float16* __restrict__ h1prev, // [512][512]
    const _Float16* __restrict__ WT,     // [128][512]
    const float* __restrict__ bout,
    const float* __restrict__ x,         // [512][256][128]
    int t,
    _Float16* __restrict__ cur,          // [512][128]
    float* __restrict__ outPred)         // [B*(T-1)][128] region of d_out
{
    __shared__ float sred[512 * 5];

    const int tid = threadIdx.x;
    const int wave = tid >> 6, l = tid & 63;
    const int pr = blockIdx.x >> 3;       // b-row tile 0..31
    const int pc = blockIdx.x & 7;        // d-col tile 0..7
    const int arow = (pr * 16 + (l & 15)) * 512;
    const int brow = (pc * 16 + (l & 15)) * 512;
    const int kof = (l >> 4) << 3;

    f32x4 acc = {};
#pragma unroll
    for (int kk = 0; kk < 2; ++kk) {
        int k = wave * 64 + kk * 32 + kof;
        f16x8 a = *reinterpret_cast<const f16x8*>(h1prev + arow + k);
        f16x8 b = *reinterpret_cast<const f16x8*>(WT + brow + k);
        // swapped: lane holds b=pr*16+(l&15), d=pc*16+(l>>4)*4+r
        acc = __builtin_amdgcn_mfma_f32_16x16x32_f16(b, a, acc, 0, 0, 0);
    }
    {
        float* sr = &sred[(wave * 64 + l) * 5];
#pragma unroll
        for (int r = 0; r < 4; ++r) sr[r] = acc[r];
    }
    __syncthreads();
    if (wave == 0) {
#pragma unroll
        for (int w = 1; w < 8; ++w) {
            const float* sr = &sred[(w * 64 + l) * 5];
#pragma unroll
            for (int r = 0; r < 4; ++r) acc[r] += sr[r];
        }
        const int b = pr * 16 + (l & 15);
        const int colb = pc * 16 + ((l >> 4) << 2);
        f32x4 bo4 = *reinterpret_cast<const f32x4*>(&bout[colb]);
        f32x4 xv4 = *reinterpret_cast<const f32x4*>(&x[((size_t)b * T_ + t) * D_ + colb]);
        f32x4 p4;
        union { _Float16 h[4]; u64 u; } ch;
#pragma unroll
        for (int r = 0; r < 4; ++r) {
            float pred = acc[r] + bo4[r];
            p4[r] = pred;
            float cv = (xv4[r] == 128.0f) ? pred : xv4[r];
            ch.h[r] = (_Float16)cv;
        }
        *reinterpret_cast<f32x4*>(&outPred[((size_t)b * (T_ - 1) + (t - 1)) * D_ + colb]) = p4;
        *reinterpret_cast<u64*>(&cur[b * D_ + colb]) = ch.u;
    }
}

extern "C" void kernel_launch(void* const* d_in, const int* in_sizes, int n_in,
                              void* d_out, int out_size, void* d_ws, size_t ws_size,
                              hipStream_t stream)
{
    const float* x  = (const float*)d_in[0];
    const float* k0 = (const float*)d_in[1];
    const float* r0 = (const float*)d_in[2];
    const float* b0 = (const float*)d_in[3];
    const float* k1 = (const float*)d_in[4];
    const float* r1 = (const float*)d_in[5];
    const float* b1 = (const float*)d_in[6];
    const float* W  = (const float*)d_in[7];
    const float* bo = (const float*)d_in[8];
    float* out = (float*)d_out;

    char* ws = (char*)d_ws;
    size_t off = 0;
    auto alloc = [&](size_t bytes) { void* p = ws + off; off += (bytes + 255) & ~255ull; return p; };
    _Float16* wB0T = (_Float16*)alloc((size_t)2048 * 640 * 2);
    _Float16* wB1T = (_Float16*)alloc((size_t)2048 * 1024 * 2);
    _Float16* wWT  = (_Float16*)alloc((size_t)128 * 512 * 2);
    _Float16* cur  = (_Float16*)alloc((size_t)B_ * D_ * 2);
    _Float16* h0[2] = { (_Float16*)alloc((size_t)B_ * H_ * 2), (_Float16*)alloc((size_t)B_ * H_ * 2) };
    _Float16* h1[2] = { (_Float16*)alloc((size_t)B_ * H_ * 2), (_Float16*)alloc((size_t)B_ * H_ * 2) };
    float* c0 = (float*)alloc((size_t)B_ * H_ * 4);
    float* c1 = (float*)alloc((size_t)B_ * H_ * 4);

    k_convert<<<2048, 256, 0, stream>>>(k0, r0, k1, r1, W, wB0T, wB1T, wWT);
    k_init<<<1024, 256, 0, stream>>>(x, cur, h0[0], h0[1], h1[0], h1[1], c0, c1);

    float* lastcell = out + (size_t)B_ * (T_ - 1) * D_;

    for (int t = 0; t < T_; ++t) {
        int cu = t & 1, pv = cu ^ 1;
        if (t > 0)
            k_pred<<<256, 512, 0, stream>>>(h1[pv], wWT, bo, x, t, cur, out);
        k_layer<640, 128><<<dim3(32, 8), 512, 0, stream>>>(
            cur, D_, h0[pv], H_, wB0T, b0, c0, h0[cu], nullptr);
        k_layer<1024, 512><<<dim3(32, 8), 512, 0, stream>>>(
            h0[cu], H_, h1[pv], H_, wB1T, b1, c1, h1[cu],
            (t == T_ - 1) ? lastcell : nullptr);
    }
}